// Round 9
// baseline (315.504 us; speedup 1.0000x reference)
//
#include <hip/hip_runtime.h>
#include <hip/hip_bf16.h>

#define BB 64
#define SS 4096
#define EE 128   // EMB_DIM
#define DD 128   // DEC_DIM
#define FAN 256
#define TILES 4            // 64-row s-tiles per logits block
#define ROWS (TILES * 64)  // 256 s-rows per block
#define GG (SS / ROWS)     // 16 blocks per b-row

typedef __bf16 bf16x8 __attribute__((ext_vector_type(8)));
typedef unsigned short u16x8 __attribute__((ext_vector_type(8)));
typedef float f32x4 __attribute__((ext_vector_type(4)));

__device__ inline bf16x8 ld_frag_lds(const unsigned char* p) {
    union { u16x8 u; bf16x8 b; } c;
    c.u = *(const u16x8*)p;
    return c.b;
}

__device__ inline uint2 f4_to_bf4(float4 f) {
    union { __hip_bfloat162 b; unsigned u; } lo, hi;
    lo.b = __float22bfloat162_rn(make_float2(f.x, f.y));
    hi.b = __float22bfloat162_rn(make_float2(f.z, f.w));
    return make_uint2(lo.u, hi.u);
}

__device__ inline float tanh_fast(float x) {
    float ax = fabsf(x);
    float e = __expf(-2.0f * ax);
    float t = (1.0f - e) * __builtin_amdgcn_rcpf(1.0f + e);
    return x < 0.0f ? -t : t;
}

// ---------------------------------------------------------------------------
// Kernel 1: h_proj (fp32), We -> bf16 PRE-SWIZZLED LDS image, v copy,
// per-b completion counters zeroed (128B-strided, one line per b).
// Swizzle: byte offset for (d, ebyte) is d*256 + (ebyte ^ ((d&7)<<4)).
// grid 64 x 256
// ---------------------------------------------------------------------------
__global__ __launch_bounds__(256) void prep_kernel(
        const float* __restrict__ hidden, const float* __restrict__ W_attn,
        const float* __restrict__ b_attn, const float* __restrict__ v_w,
        float* __restrict__ hproj, unsigned char* __restrict__ Wb,
        float* __restrict__ v_out, unsigned* __restrict__ cnt) {
    const int b = blockIdx.x;
    const int t = threadIdx.x;
    if (t == 0) cnt[b * 32] = 0u;        // re-zeroed every replay, pre-logits
    if (t < 128) {
        float acc = b_attn[t];
        const float4* hrow = (const float4*)(hidden + b * DD);
        const float4* wrow = (const float4*)(W_attn + t * FAN);
        #pragma unroll
        for (int e = 0; e < 32; e++) {
            float4 h = hrow[e], w = wrow[e];
            acc += h.x * w.x + h.y * w.y + h.z * w.z + h.w * w.w;
        }
        hproj[b * DD + t] = acc;
        if (b == 0) v_out[t] = v_w[t];
    } else {
        int tt = t - 128;
        int d  = 2 * b + (tt >> 6);
        int e0 = (tt & 63) * 2;          // even element index; writes pair (e0,e0+1)
        float2 src = *(const float2*)(W_attn + d * FAN + DD + e0);
        union { __hip_bfloat162 bb; unsigned u; } c;
        c.bb = __float22bfloat162_rn(src);
        unsigned off = (unsigned)(d * 256)
                     + (((unsigned)(e0 * 2)) ^ (((unsigned)d & 7u) << 4));
        *(unsigned*)(Wb + off) = c.u;
    }
}

// ---------------------------------------------------------------------------
// Kernel 2 (R4 hot loop UNCHANGED + fused last-block normalization):
// out[b][s] = exp(v . tanh(hproj[b] + X[s] @ We^T)) (0 if masked);
// the 16th block of each b to finish reduces that b's 64 psums and
// normalizes the row in-place (canonical threadfence-reduction pattern).
// Max-free exp safe: |logit| <= ||v||_1 <= 128/sqrt(128) = 11.31.
// grid (16, 64) x 256.
// ---------------------------------------------------------------------------
__global__ __launch_bounds__(256, 4) void logits_kernel(
        const float* __restrict__ seq_embs, const int* __restrict__ mask,
        const float* __restrict__ hproj, const unsigned char* __restrict__ Wb,
        const float* __restrict__ v, float* __restrict__ out,
        float* __restrict__ psums, unsigned* __restrict__ cnt) {
    __shared__ __attribute__((aligned(1024))) unsigned char Ws[DD * EE * 2]; // 32 KB

    const int b    = blockIdx.y;
    const int g    = blockIdx.x;
    const int tid  = threadIdx.x;
    const int wave = tid >> 6;
    const int lane = tid & 63;
    const int m    = lane & 15;
    const int quad = lane >> 4;
    const int arow = wave * 16 + m;       // this lane's s-row within each tile

    // --- Stage swizzled We image via direct global->LDS DMA (identity copy).
    #pragma unroll
    for (int j = 0; j < 8; j++) {
        const int c = wave * 8 + j;
        __builtin_amdgcn_global_load_lds(
            (const __attribute__((address_space(1))) unsigned int*)(Wb + c * 1024 + lane * 16),
            (__attribute__((address_space(3))) unsigned int*)(Ws + c * 1024),
            16, 0, 0);
    }

    const int* __restrict__ mask_g = mask + (size_t)b * SS + g * ROWS;
    const float* __restrict__ xbase = seq_embs
        + (size_t)(g * ROWS + arow) * (BB * EE)
        + (size_t)b * EE + quad * 8;

    // --- Prefetch tile 0's mask + A-frags while the staging DMA is in flight.
    int am[2];
    int4 mq[2];
    bf16x8 af[2][4];
    {
        am[0] = mask_g[arow];
        mq[0] = *(const int4*)(mask_g + wave * 16 + quad * 4);
        const float* xrow = xbase;
        #pragma unroll
        for (int kk = 0; kk < 4; kk++) {
            union { uint4 q; bf16x8 bf; } c;
            c.q = make_uint4(0u, 0u, 0u, 0u);
            if (am[0] != 0) {
                float4 f0 = *(const float4*)(xrow + kk * 32);
                float4 f1 = *(const float4*)(xrow + kk * 32 + 4);
                uint2 a = f4_to_bf4(f0), bq = f4_to_bf4(f1);
                c.q = make_uint4(a.x, a.y, bq.x, bq.y);
            }
            af[0][kk] = c.bf;
        }
    }

    // --- Per-lane epilogue constants (L2-hot).
    float hp_r[8], v_r[8];
    #pragma unroll
    for (int t = 0; t < 8; t++) {
        hp_r[t] = hproj[b * DD + t * 16 + m];
        v_r[t]  = v[t * 16 + m];
    }

    __syncthreads();   // drains vmcnt(0): staging DMA + tile-0 A-loads complete

    const unsigned sw = ((unsigned)(m & 7)) << 4;   // read-side XOR (matches prep)
    float blocksum = 0.0f;

    #pragma unroll
    for (int tile = 0; tile < TILES; tile++) {
        const int cur = tile & 1;
        // Prefetch next tile's mask + A-frags (independent of this tile's MFMA).
        if (tile + 1 < TILES) {
            const int nxt = cur ^ 1;
            am[nxt] = mask_g[(tile + 1) * 64 + arow];
            mq[nxt] = *(const int4*)(mask_g + (tile + 1) * 64 + wave * 16 + quad * 4);
            const float* xrow = xbase + (size_t)((tile + 1) * 64) * (BB * EE);
            #pragma unroll
            for (int kk = 0; kk < 4; kk++) {
                union { uint4 q; bf16x8 bf; } c;
                c.q = make_uint4(0u, 0u, 0u, 0u);
                if (am[nxt] != 0) {
                    float4 f0 = *(const float4*)(xrow + kk * 32);
                    float4 f1 = *(const float4*)(xrow + kk * 32 + 4);
                    uint2 a = f4_to_bf4(f0), bq = f4_to_bf4(f1);
                    c.q = make_uint4(a.x, a.y, bq.x, bq.y);
                }
                af[nxt][kk] = c.bf;
            }
        }

        // --- MFMA: 64 s-rows x 128 d, K=128. 8 independent acc chains.
        f32x4 acc[8];
        #pragma unroll
        for (int t = 0; t < 8; t++) acc[t] = (f32x4){0.f, 0.f, 0.f, 0.f};
        #pragma unroll
        for (int kk = 0; kk < 4; kk++) {
            const unsigned cb = ((unsigned)(kk * 64 + quad * 16)) ^ sw;
            #pragma unroll
            for (int t = 0; t < 8; t++) {
                bf16x8 bf = ld_frag_lds(Ws + (unsigned)((t * 16 + m) * 256) + cb);
                acc[t] = __builtin_amdgcn_mfma_f32_16x16x32_bf16(af[cur][kk], bf, acc[t], 0, 0, 0);
            }
        }

        // --- Deferred epilogue: logit -> exp, mask-guarded (skip ~50% rows).
        const int mqa[4] = {mq[cur].x, mq[cur].y, mq[cur].z, mq[cur].w};
        float red[4];
        #pragma unroll
        for (int r = 0; r < 4; r++) {
            float red_r = 0.0f;
            if (mqa[r] != 0) {   // uniform across the 16-lane m-group: shfl-safe
                float part = 0.f;
                #pragma unroll
                for (int t = 0; t < 8; t++)
                    part += v_r[t] * tanh_fast(hp_r[t] + acc[t][r]);
                part += __shfl_xor(part, 1);
                part += __shfl_xor(part, 2);
                part += __shfl_xor(part, 4);
                part += __shfl_xor(part, 8);
                red_r = __expf(part);
            }
            red[r] = red_r;
            blocksum += red_r;
        }
        if (m == 0) {
            *(float4*)&out[(size_t)b * SS + g * ROWS + tile * 64
                           + wave * 16 + quad * 4] =
                make_float4(red[0], red[1], red[2], red[3]);
        }
    }

    // One plain store per wave (no atomics, no hot-line contention).
    blocksum += __shfl_xor(blocksum, 16);
    blocksum += __shfl_xor(blocksum, 32);
    if (lane == 0) psums[(b * GG + g) * 4 + wave] = blocksum;

    // --- Fused normalization: last block of this b reduces psums and scales
    // the row in place. Canonical pattern: store -> threadfence (release) ->
    // syncthreads -> one atomic -> last block acquires and reads.
    __threadfence();
    __syncthreads();                      // Ws is dead from here: reuse as flags
    volatile int*   s_last = (volatile int*)&Ws[0];
    volatile float* s_inv  = (volatile float*)&Ws[4];
    if (tid == 0) {
        unsigned old = atomicAdd(&cnt[b * 32], 1u);
        *s_last = (old == (unsigned)(GG - 1)) ? 1 : 0;
    }
    __syncthreads();
    if (*s_last) {                        // block-uniform branch
        __threadfence();                  // acquire: other blocks' out/psums
        if (tid < 64) {
            float p = psums[b * 64 + tid];
            #pragma unroll
            for (int off = 32; off >= 1; off >>= 1)
                p += __shfl_xor(p, off);
            if (tid == 0) *s_inv = 1.0f / p;
        }
        __syncthreads();
        const float inv = *s_inv;
        float* row = out + (size_t)b * SS;
        #pragma unroll
        for (int i = 0; i < 4; i++) {
            float4 vv4 = *(float4*)&row[(size_t)(i * 256 + tid) * 4];
            vv4.x *= inv; vv4.y *= inv; vv4.z *= inv; vv4.w *= inv;
            *(float4*)&row[(size_t)(i * 256 + tid) * 4] = vv4;
        }
    }
}

extern "C" void kernel_launch(void* const* d_in, const int* in_sizes, int n_in,
                              void* d_out, int out_size, void* d_ws, size_t ws_size,
                              hipStream_t stream) {
    const float* hidden   = (const float*)d_in[0];
    const float* seq_embs = (const float*)d_in[1];
    const int*   mask     = (const int*)d_in[2];
    const float* W_attn   = (const float*)d_in[3];
    const float* b_attn   = (const float*)d_in[4];
    const float* v_w      = (const float*)d_in[5];
    float* out = (float*)d_out;

    float*         hproj = (float*)d_ws;                            // 32 KB
    unsigned char* Wb    = (unsigned char*)d_ws + 32768;            // 32 KB swizzled image
    float*         vv    = (float*)((char*)d_ws + 65536);           // 512 B
    float*         psums = (float*)((char*)d_ws + 66048);           // 16 KB (64 x 64)
    unsigned*      cnt   = (unsigned*)((char*)d_ws + 82432);        // 8 KB (64 x 128B)

    prep_kernel<<<64, 256, 0, stream>>>(hidden, W_attn, b_attn, v_w, hproj, Wb, vv, cnt);
    dim3 grid(GG, BB);                 // (16, 64)
    logits_kernel<<<grid, 256, 0, stream>>>(seq_embs, mask, hproj, Wb, vv, out, psums, cnt);
}

// Round 10
// 211.410 us; speedup vs baseline: 1.4924x; 1.4924x over previous
//
#include <hip/hip_runtime.h>
#include <hip/hip_bf16.h>

#define BB 64
#define SS 4096
#define EE 128   // EMB_DIM
#define DD 128   // DEC_DIM
#define FAN 256
#define TILES 4            // 64-row s-tiles per logits block
#define ROWS (TILES * 64)  // 256 s-rows per block

typedef __bf16 bf16x8 __attribute__((ext_vector_type(8)));
typedef unsigned short u16x8 __attribute__((ext_vector_type(8)));
typedef float f32x4 __attribute__((ext_vector_type(4)));

__device__ inline bf16x8 ld_frag_lds(const unsigned char* p) {
    union { u16x8 u; bf16x8 b; } c;
    c.u = *(const u16x8*)p;
    return c.b;
}

__device__ inline uint2 f4_to_bf4(float4 f) {
    union { __hip_bfloat162 b; unsigned u; } lo, hi;
    lo.b = __float22bfloat162_rn(make_float2(f.x, f.y));
    hi.b = __float22bfloat162_rn(make_float2(f.z, f.w));
    return make_uint2(lo.u, hi.u);
}

__device__ inline float tanh_fast(float x) {
    float ax = fabsf(x);
    float e = __expf(-2.0f * ax);
    float t = (1.0f - e) * __builtin_amdgcn_rcpf(1.0f + e);
    return x < 0.0f ? -t : t;
}

// ---------------------------------------------------------------------------
// Kernel 1: h_proj (fp32), We -> bf16 PRE-SWIZZLED LDS image, v copy.
// Swizzle: byte offset for (d, ebyte) is d*256 + (ebyte ^ ((d&7)<<4)).
// grid 64 x 256
// ---------------------------------------------------------------------------
__global__ __launch_bounds__(256) void prep_kernel(
        const float* __restrict__ hidden, const float* __restrict__ W_attn,
        const float* __restrict__ b_attn, const float* __restrict__ v_w,
        float* __restrict__ hproj, unsigned char* __restrict__ Wb,
        float* __restrict__ v_out) {
    const int b = blockIdx.x;
    const int t = threadIdx.x;
    if (t < 128) {
        float acc = b_attn[t];
        const float4* hrow = (const float4*)(hidden + b * DD);
        const float4* wrow = (const float4*)(W_attn + t * FAN);
        #pragma unroll
        for (int e = 0; e < 32; e++) {
            float4 h = hrow[e], w = wrow[e];
            acc += h.x * w.x + h.y * w.y + h.z * w.z + h.w * w.w;
        }
        hproj[b * DD + t] = acc;
        if (b == 0) v_out[t] = v_w[t];
    } else {
        int tt = t - 128;
        int d  = 2 * b + (tt >> 6);
        int e0 = (tt & 63) * 2;          // even element index; writes pair (e0,e0+1)
        float2 src = *(const float2*)(W_attn + d * FAN + DD + e0);
        union { __hip_bfloat162 bb; unsigned u; } c;
        c.bb = __float22bfloat162_rn(src);
        unsigned off = (unsigned)(d * 256)
                     + (((unsigned)(e0 * 2)) ^ (((unsigned)d & 7u) << 4));
        *(unsigned*)(Wb + off) = c.u;
    }
}

// ---------------------------------------------------------------------------
// Kernel 2 (R4 configuration — measured optimum, 211.4 us total):
// out[b][s] = exp(v . tanh(hproj[b] + X[s] @ We^T)) (0 if masked).
// Max-free exp safe: |logit| <= ||v||_1 <= 128/sqrt(128) = 11.31.
// - DMA-staged swizzled Ws (identity global->LDS copy, bank-even reads)
// - kk-outer / t-inner MFMA: 8 independent acc chains
// - depth-1 double-buffered A-prefetch (deeper measured neutral, R7)
// - mask-guarded deferred epilogue (skip ~50% rows)
// - plain-store psums (atomics to hot lines cost −17 us, R3;
//   threadfence-fused norm cost −104 us via L2 writeback, R9)
// grid (16, 64) x 256 = 1024 blocks = 4/CU, 16 waves/CU (R6: never trade
// occupancy; R8: more blocks = more staging, −10 us).
// ---------------------------------------------------------------------------
__global__ __launch_bounds__(256, 4) void logits_kernel(
        const float* __restrict__ seq_embs, const int* __restrict__ mask,
        const float* __restrict__ hproj, const unsigned char* __restrict__ Wb,
        const float* __restrict__ v, float* __restrict__ out,
        float* __restrict__ psums) {
    __shared__ __attribute__((aligned(1024))) unsigned char Ws[DD * EE * 2]; // 32 KB

    const int b    = blockIdx.y;
    const int g    = blockIdx.x;
    const int tid  = threadIdx.x;
    const int wave = tid >> 6;
    const int lane = tid & 63;
    const int m    = lane & 15;
    const int quad = lane >> 4;
    const int arow = wave * 16 + m;       // this lane's s-row within each tile

    // --- Stage swizzled We image via direct global->LDS DMA (identity copy).
    #pragma unroll
    for (int j = 0; j < 8; j++) {
        const int c = wave * 8 + j;
        __builtin_amdgcn_global_load_lds(
            (const __attribute__((address_space(1))) unsigned int*)(Wb + c * 1024 + lane * 16),
            (__attribute__((address_space(3))) unsigned int*)(Ws + c * 1024),
            16, 0, 0);
    }

    const int* __restrict__ mask_g = mask + (size_t)b * SS + g * ROWS;
    const float* __restrict__ xbase = seq_embs
        + (size_t)(g * ROWS + arow) * (BB * EE)
        + (size_t)b * EE + quad * 8;

    // --- Prefetch tile 0's mask + A-frags while the staging DMA is in flight.
    int am[2];
    int4 mq[2];
    bf16x8 af[2][4];
    {
        am[0] = mask_g[arow];
        mq[0] = *(const int4*)(mask_g + wave * 16 + quad * 4);
        const float* xrow = xbase;
        #pragma unroll
        for (int kk = 0; kk < 4; kk++) {
            union { uint4 q; bf16x8 bf; } c;
            c.q = make_uint4(0u, 0u, 0u, 0u);
            if (am[0] != 0) {
                float4 f0 = *(const float4*)(xrow + kk * 32);
                float4 f1 = *(const float4*)(xrow + kk * 32 + 4);
                uint2 a = f4_to_bf4(f0), bq = f4_to_bf4(f1);
                c.q = make_uint4(a.x, a.y, bq.x, bq.y);
            }
            af[0][kk] = c.bf;
        }
    }

    // --- Per-lane epilogue constants (L2-hot).
    float hp_r[8], v_r[8];
    #pragma unroll
    for (int t = 0; t < 8; t++) {
        hp_r[t] = hproj[b * DD + t * 16 + m];
        v_r[t]  = v[t * 16 + m];
    }

    __syncthreads();   // drains vmcnt(0): staging DMA + tile-0 A-loads complete

    const unsigned sw = ((unsigned)(m & 7)) << 4;   // read-side XOR (matches prep)
    float blocksum = 0.0f;

    #pragma unroll
    for (int tile = 0; tile < TILES; tile++) {
        const int cur = tile & 1;
        // Prefetch next tile's mask + A-frags (independent of this tile's MFMA).
        if (tile + 1 < TILES) {
            const int nxt = cur ^ 1;
            am[nxt] = mask_g[(tile + 1) * 64 + arow];
            mq[nxt] = *(const int4*)(mask_g + (tile + 1) * 64 + wave * 16 + quad * 4);
            const float* xrow = xbase + (size_t)((tile + 1) * 64) * (BB * EE);
            #pragma unroll
            for (int kk = 0; kk < 4; kk++) {
                union { uint4 q; bf16x8 bf; } c;
                c.q = make_uint4(0u, 0u, 0u, 0u);
                if (am[nxt] != 0) {
                    float4 f0 = *(const float4*)(xrow + kk * 32);
                    float4 f1 = *(const float4*)(xrow + kk * 32 + 4);
                    uint2 a = f4_to_bf4(f0), bq = f4_to_bf4(f1);
                    c.q = make_uint4(a.x, a.y, bq.x, bq.y);
                }
                af[nxt][kk] = c.bf;
            }
        }

        // --- MFMA: 64 s-rows x 128 d, K=128. 8 independent acc chains.
        f32x4 acc[8];
        #pragma unroll
        for (int t = 0; t < 8; t++) acc[t] = (f32x4){0.f, 0.f, 0.f, 0.f};
        #pragma unroll
        for (int kk = 0; kk < 4; kk++) {
            const unsigned cb = ((unsigned)(kk * 64 + quad * 16)) ^ sw;
            #pragma unroll
            for (int t = 0; t < 8; t++) {
                bf16x8 bf = ld_frag_lds(Ws + (unsigned)((t * 16 + m) * 256) + cb);
                acc[t] = __builtin_amdgcn_mfma_f32_16x16x32_bf16(af[cur][kk], bf, acc[t], 0, 0, 0);
            }
        }

        // --- Deferred epilogue: logit -> exp, mask-guarded (skip ~50% rows).
        const int mqa[4] = {mq[cur].x, mq[cur].y, mq[cur].z, mq[cur].w};
        float red[4];
        #pragma unroll
        for (int r = 0; r < 4; r++) {
            float red_r = 0.0f;
            if (mqa[r] != 0) {   // uniform across the 16-lane m-group: shfl-safe
                float part = 0.f;
                #pragma unroll
                for (int t = 0; t < 8; t++)
                    part += v_r[t] * tanh_fast(hp_r[t] + acc[t][r]);
                part += __shfl_xor(part, 1);
                part += __shfl_xor(part, 2);
                part += __shfl_xor(part, 4);
                part += __shfl_xor(part, 8);
                red_r = __expf(part);
            }
            red[r] = red_r;
            blocksum += red_r;
        }
        if (m == 0) {
            *(float4*)&out[(size_t)b * SS + g * ROWS + tile * 64
                           + wave * 16 + quad * 4] =
                make_float4(red[0], red[1], red[2], red[3]);
        }
    }

    // One plain store per wave (no atomics, no hot-line contention).
    blocksum += __shfl_xor(blocksum, 16);
    blocksum += __shfl_xor(blocksum, 32);
    if (lane == 0) psums[(b * 16 + g) * 4 + wave] = blocksum;
}

// ---------------------------------------------------------------------------
// Kernel 3: reduce the 64 per-wave partials of row b, then out[b][s] *= inv.
// grid (4, 64) x 256.
// ---------------------------------------------------------------------------
__global__ __launch_bounds__(256) void norm_kernel(
        float* __restrict__ out, const float* __restrict__ psums) {
    const int b = blockIdx.y;
    const int tid = threadIdx.x;
    const int lane = tid & 63;
    float p = psums[b * 64 + lane];          // 64 partials, L2-hot
    #pragma unroll
    for (int off = 32; off >= 1; off >>= 1)
        p += __shfl_xor(p, off);
    const float inv = 1.0f / p;              // all lanes hold the full row sum
    const int i = (blockIdx.x * 256 + tid) * 4;
    float4 v = *(float4*)&out[(size_t)b * SS + i];
    v.x *= inv; v.y *= inv; v.z *= inv; v.w *= inv;
    *(float4*)&out[(size_t)b * SS + i] = v;
}

extern "C" void kernel_launch(void* const* d_in, const int* in_sizes, int n_in,
                              void* d_out, int out_size, void* d_ws, size_t ws_size,
                              hipStream_t stream) {
    const float* hidden   = (const float*)d_in[0];
    const float* seq_embs = (const float*)d_in[1];
    const int*   mask     = (const int*)d_in[2];
    const float* W_attn   = (const float*)d_in[3];
    const float* b_attn   = (const float*)d_in[4];
    const float* v_w      = (const float*)d_in[5];
    float* out = (float*)d_out;

    float*         hproj = (float*)d_ws;                            // 32 KB
    unsigned char* Wb    = (unsigned char*)d_ws + 32768;            // 32 KB swizzled image
    float*         vv    = (float*)((char*)d_ws + 65536);           // 512 B
    float*         psums = (float*)((char*)d_ws + 66048);           // 16 KB (64 x 64)

    prep_kernel<<<64, 256, 0, stream>>>(hidden, W_attn, b_attn, v_w, hproj, Wb, vv);
    dim3 grid(SS / ROWS, BB);          // (16, 64)
    logits_kernel<<<grid, 256, 0, stream>>>(seq_embs, mask, hproj, Wb, vv, out, psums);
    dim3 ngrid(SS / (256 * 4), BB);    // (4, 64)
    norm_kernel<<<ngrid, 256, 0, stream>>>(out, psums);
}